// Round 11
// baseline (125.734 us; speedup 1.0000x reference)
//
#include <hip/hip_runtime.h>
#include <hip/hip_bf16.h>

// Problem: B=512, S=256, E=384, H=64.
// d_in: x [B,S,E] f32; Wq,Wk,Wv [E,H] f32.  d_out: [B,S,H] f32.
// ws: [0, 147456) wfrag bf16 (only region used).
//
// FUSED v11 = v10 (57.0us) made PERSISTENT: grid 256, each block runs
// batches b and b+256. The attention phase (zero barriers, HBM-idle) now
// hides the next batch's x traffic:
//  (a) chunk-0 pre-stage: loadch(bB,0) issues at attn(bA) start, writech
//      lands between the two attention tile passes -> proj(bB)'s prologue
//      is free.
//  (b) L3-warm prefetch: 6 strided dword loads/thread (1 per 128B line)
//      cover bB's remaining x; sunk via asm. HBM->L3 during idle window.
// af is re-declared INSIDE the batch loop (SYNC_LDS "memory" clobbers
// prevent CSE) so its live range never overlaps attention's s[16] --
// avoiding the v5/v6/v8 allocator-spill failure.

#define NB   512
#define SS   256
#define EE   384
#define HH   64

#define PR16  16            // x rows staged per chunk per group
#define LROW  392           // staging row stride in shorts (384 data + 8 pad)
#define XLSZ  (PR16 * LROW) // 6272 shorts per staging buffer

// lgkm-only barrier: LDS writes retired, global loads ride through (v10-verified).
#define SYNC_LDS() asm volatile("s_waitcnt lgkmcnt(0)\n\ts_barrier" ::: "memory")

typedef short bf16x8 __attribute__((ext_vector_type(8)));
typedef float f32x4  __attribute__((ext_vector_type(4)));

__device__ __forceinline__ short f2bf(float f) {
  union { float f; unsigned u; } x; x.f = f;
  unsigned r = x.u + 0x7fffu + ((x.u >> 16) & 1u);
  return (short)(r >> 16);
}

// ---------------- prep: W -> fragment-ordered bf16 (unchanged) ----------------
// wfrag[((ks*12+nf)*64 + lane)*8 + j] = Wcat[ks*32 + (lane>>4)*8 + j][nf*16 + (lane&15)]
__global__ __launch_bounds__(256) void prep_w_kernel(
    const float* __restrict__ Wq, const float* __restrict__ Wk,
    const float* __restrict__ Wv, short* __restrict__ wfrag) {
  int t = blockIdx.x * 256 + threadIdx.x;
  if (t >= 12 * 12 * 64) return;
  int ks  = t / (12 * 64);
  int rem = t % (12 * 64);
  int nf  = rem / 64;
  int l   = rem % 64;
  int l15 = l & 15, lhi = l >> 4;
  int ncat = nf * 16 + l15;
  const float* W = (ncat < 64) ? Wq : (ncat < 128 ? Wk : Wv);
  int n = ncat & 63;
  short* dst = wfrag + (size_t)t * 8;
#pragma unroll
  for (int j = 0; j < 8; ++j) {
    int kk = ks * 32 + lhi * 8 + j;
    dst[j] = f2bf(W[kk * 64 + n]);
  }
}

// ---------------- fused persistent: one block = two batches, 8 waves, 148 KB LDS ----------------
__global__ __launch_bounds__(512, 2) void fused_kernel(
    const float* __restrict__ x, const short* __restrict__ wfrag,
    float* __restrict__ out) {
  // Ql swizzled: elem (row,h) at Ql[row*64 + (h ^ ((row&7)<<3))]       (v2..v10-verified)
  // Kl swizzled: elem (row,h) at Kl[row*64 + (h ^ (srow<<3))], srow=((row&8)>>1)|(row&3)
  // Vt swizzled: elem (h,row) at Vt[h*256 + (row ^ ((h&7)<<3))]
  // xst: per group g, dbuf of 16-row tiles, padded stride LROW=392
  __shared__ __align__(16) short Ql[SS * HH];    // 32 KB
  __shared__ __align__(16) short Kl[SS * HH];    // 32 KB
  __shared__ __align__(16) short Vt[HH * SS];    // 32 KB
  __shared__ __align__(16) short xst[4 * XLSZ];  // 49 KB -> 148480 B total

  int b0   = blockIdx.x;                         // handles batches b0 and b0+256
  int tid  = threadIdx.x;
  int lane = tid & 63, wv = tid >> 6;            // wv in [0,8)
  int l15  = lane & 15, lhi = lane >> 4;
  int sw   = l15 & 7;
  int g    = wv >> 2;                            // row group: rows [g*128, g*128+128)
  int wg   = wv & 3;                             // col-split role: h-tiles f = wg*3+ht
  int tg   = tid & 255;                          // thread index within group

  f32x4 st[6];
  auto loadch = [&](const float* xgp, int ch) {  // 16 rows = 24 KB f32/group, contiguous
    const float* p0 = xgp + (size_t)ch * PR16 * EE;
#pragma unroll
    for (int i = 0; i < 3; ++i) {
      const f32x4* p = (const f32x4*)(p0 + (size_t)(tg + 256 * i) * 8);
      st[2 * i]     = p[0];
      st[2 * i + 1] = p[1];
    }
  };
  auto writech = [&](short* xl) {  // regs -> bf16 -> padded LDS tile (v2-verified)
#pragma unroll
    for (int i = 0; i < 3; ++i) {
      int c = tg + 256 * i;          // 8-float group: row = c/48, cg = c%48
      int row = c / 48, cg = c % 48;
      union { bf16x8 vv; __hip_bfloat162 h2[4]; } u;
      u.h2[0] = __float22bfloat162_rn(make_float2(st[2*i][0],   st[2*i][1]));
      u.h2[1] = __float22bfloat162_rn(make_float2(st[2*i][2],   st[2*i][3]));
      u.h2[2] = __float22bfloat162_rn(make_float2(st[2*i+1][0], st[2*i+1][1]));
      u.h2[3] = __float22bfloat162_rn(make_float2(st[2*i+1][2], st[2*i+1][3]));
      *(bf16x8*)(xl + row * LROW + cg * 8) = u.vv;
    }
  };

  // one attention tile: scores -> softmax -> in-lane P -> PV -> store (v10-verified)
  auto attn_tile = [&](int rt, size_t obase) {
    int qrow0 = rt * 16;
    int twp   = (rt + 2) & ~1;       // even # of interleaved 16-row k-tiles
    int nk    = twp >> 1;            // 32-k PV chunks
    int qg    = qrow0 + l15;         // this lane's q-row (P lives at q=l15)

    int qlrow = qrow0 + l15;
    bf16x8 qa0 = *(const bf16x8*)(Ql + qlrow * 64 + ((lhi * 8) ^ ((qlrow & 7) << 3)));
    bf16x8 qa1 = *(const bf16x8*)(Ql + qlrow * 64 + ((32 + lhi * 8) ^ ((qlrow & 7) << 3)));

    f32x4 s[16];
#pragma unroll
    for (int t = 0; t < 16; ++t) {
      if (t >= twp) continue;
      int kc = (t >> 1) * 32 + ((l15 >> 2) << 3) + ((t & 1) << 2) + (l15 & 3);
      const short* kp = Kl + kc * 64;
      bf16x8 kb0 = *(const bf16x8*)(kp + ((lhi * 8) ^ (sw << 3)));
      bf16x8 kb1 = *(const bf16x8*)(kp + ((32 + lhi * 8) ^ (sw << 3)));
      __builtin_amdgcn_s_setprio(1);
      f32x4 a = (f32x4){0.f, 0.f, 0.f, 0.f};
      a = __builtin_amdgcn_mfma_f32_16x16x32_bf16(kb0, qa0, a, 0, 0, 0);
      a = __builtin_amdgcn_mfma_f32_16x16x32_bf16(kb1, qa1, a, 0, 0, 0);
      __builtin_amdgcn_s_setprio(0);
#pragma unroll
      for (int r = 0; r < 4; ++r) {
        int kg = (t >> 1) * 32 + lhi * 8 + ((t & 1) << 2) + r;
        s[t][r] = (kg <= qg) ? a[r] * 0.125f : -INFINITY;
      }
    }

    float mx = -3.0e38f;
#pragma unroll
    for (int t = 0; t < 16; ++t) {
      if (t >= twp) continue;
#pragma unroll
      for (int r = 0; r < 4; ++r) mx = fmaxf(mx, s[t][r]);
    }
    mx = fmaxf(mx, __shfl_xor(mx, 16));
    mx = fmaxf(mx, __shfl_xor(mx, 32));
    float sm = 0.f;
#pragma unroll
    for (int t = 0; t < 16; ++t) {
      if (t >= twp) continue;
#pragma unroll
      for (int r = 0; r < 4; ++r) {
        float p = __expf(s[t][r] - mx);    // exp(-inf)=0
        s[t][r] = p;
        sm += p;
      }
    }
    sm += __shfl_xor(sm, 16);
    sm += __shfl_xor(sm, 32);
    float inv = 1.f / sm;
    float invq[4];
#pragma unroll
    for (int r = 0; r < 4; ++r) invq[r] = __shfl(inv, lhi * 4 + r);

    f32x4 o[4];
#pragma unroll
    for (int nf = 0; nf < 4; ++nf) o[nf] = (f32x4){0.f, 0.f, 0.f, 0.f};
#pragma unroll
    for (int kc2 = 0; kc2 < 8; ++kc2) {
      if (kc2 >= nk) continue;
      union { bf16x8 v; __hip_bfloat162 h2[4]; } pu;
      pu.h2[0] = __float22bfloat162_rn(make_float2(s[2*kc2][0],   s[2*kc2][1]));
      pu.h2[1] = __float22bfloat162_rn(make_float2(s[2*kc2][2],   s[2*kc2][3]));
      pu.h2[2] = __float22bfloat162_rn(make_float2(s[2*kc2+1][0], s[2*kc2+1][1]));
      pu.h2[3] = __float22bfloat162_rn(make_float2(s[2*kc2+1][2], s[2*kc2+1][3]));
      int kofs = kc2 * 32 + lhi * 8;
      __builtin_amdgcn_s_setprio(1);
#pragma unroll
      for (int nf = 0; nf < 4; ++nf) {
        int hrow = nf * 16 + l15;
        bf16x8 vb = *(const bf16x8*)(Vt + hrow * 256 + (kofs ^ ((hrow & 7) << 3)));
        o[nf] = __builtin_amdgcn_mfma_f32_16x16x32_bf16(pu.v, vb, o[nf], 0, 0, 0);
      }
      __builtin_amdgcn_s_setprio(0);
    }

#pragma unroll
    for (int nf = 0; nf < 4; ++nf)
#pragma unroll
      for (int r = 0; r < 4; ++r) {
        int q = qrow0 + lhi * 4 + r;
        int h = nf * 16 + l15;
        out[obase + (size_t)q * HH + h] = o[nf][r] * invq[r];
      }
  };

  // ---- cold prologue for batch b0: stage chunk 0 ----
  {
    const float* xg0 = x + (size_t)b0 * SS * EE + (size_t)g * 128 * EE;
    loadch(xg0, 0);
    writech(xst + (g * 2) * XLSZ);
  }

  // ---- persistent loop over this block's two batches ----
  for (int it = 0; it < 2; ++it) {
    int b = b0 + it * 256;
    const float* xg = x + (size_t)b * SS * EE + (size_t)g * 128 * EE;

    // W fragments: re-loaded per batch (L2-hot, ~18 KB/block) so af's live
    // range stays proj-only -- never overlaps attention's s[16]. SYNC_LDS
    // "memory" clobbers prevent cross-iteration CSE.
    bf16x8 af[12][3];
#pragma unroll
    for (int ks = 0; ks < 12; ++ks)
#pragma unroll
      for (int ht = 0; ht < 3; ++ht)
        af[ks][ht] = *(const bf16x8*)(wfrag + ((size_t)(ks * 12 + wg * 3 + ht) * 64 + lane) * 8);
#pragma unroll
    for (int ks = 0; ks < 12; ++ks)
#pragma unroll
      for (int ht = 0; ht < 3; ++ht)
        asm volatile("" : "+v"(af[ks][ht]));

    // proj: 8 chunks, dbuf, one lgkm-barrier per chunk (v7/v10-verified).
    // Chunk 0 was pre-staged (cold prologue for it=0; during attention for it=1).
    for (int ch = 0; ch < 8; ++ch) {
      if (ch < 7) loadch(xg, ch + 1);  // next chunk's loads ride through the barrier
      SYNC_LDS();                      // LDS visible; vmcnt untouched
      const short* xl = xst + (g * 2 + (ch & 1)) * XLSZ;

      f32x4 acc[3];
#pragma unroll
      for (int ht = 0; ht < 3; ++ht) acc[ht] = (f32x4){0.f, 0.f, 0.f, 0.f};
#pragma unroll
      for (int ks = 0; ks < 12; ++ks) {
        bf16x8 bx = *(const bf16x8*)(xl + l15 * LROW + ks * 32 + lhi * 8);
#pragma unroll
        for (int ht = 0; ht < 3; ++ht)
          acc[ht] = __builtin_amdgcn_mfma_f32_16x16x32_bf16(af[ks][ht], bx, acc[ht], 0, 0, 0);
      }

      int row  = g * 128 + ch * PR16 + l15;
      int srow = ((row & 8) >> 1) | (row & 3);
#pragma unroll
      for (int ht = 0; ht < 3; ++ht) {
        int f = wg * 3 + ht;
        int ncat = f * 16 + lhi * 4;
        if (f < 4) {          // Q -> Ql, row&7 swizzle
          union { short4 s4; __hip_bfloat162 h2[2]; } oq;
          oq.h2[0] = __float22bfloat162_rn(make_float2(acc[ht][0], acc[ht][1]));
          oq.h2[1] = __float22bfloat162_rn(make_float2(acc[ht][2], acc[ht][3]));
          *(short4*)(Ql + row * 64 + (ncat ^ ((row & 7) << 3))) = oq.s4;
        } else if (f < 8) {   // K -> Kl, srow swizzle
          int col = ncat - 64;
          union { short4 s4; __hip_bfloat162 h2[2]; } ok;
          ok.h2[0] = __float22bfloat162_rn(make_float2(acc[ht][0], acc[ht][1]));
          ok.h2[1] = __float22bfloat162_rn(make_float2(acc[ht][2], acc[ht][3]));
          *(short4*)(Kl + row * 64 + (col ^ (srow << 3))) = ok.s4;
        } else {              // V -> Vt transposed, scalar stores
#pragma unroll
          for (int j = 0; j < 4; ++j) {
            int h = ncat - 128 + j;
            Vt[h * 256 + (row ^ ((h & 7) << 3))] = f2bf(acc[ht][j]);
          }
        }
      }
      if (ch < 7) writech(xst + (g * 2 + ((ch + 1) & 1)) * XLSZ);
    }
    SYNC_LDS();                        // Ql/Kl/Vt complete

    // ---- attention for batch b; next batch's x prefetch rides the idle window ----
    size_t obase = (size_t)b * SS * HH;
    if (it == 0) {
      const float* xgn = x + (size_t)(b0 + 256) * SS * EE + (size_t)g * 128 * EE;
      loadch(xgn, 0);                  // chunk 0 of next batch -> st (rides attn u=0)
      // L3-warm: 1 dword per 128B line over the remaining 112 rows (chunks 1..7)
      float dummy = 0.f;
      const float* px = xgn + 16 * EE;
#pragma unroll
      for (int i = 0; i < 6; ++i) {
        int c = tg + i * 256;
        if (c < 1344) dummy += px[(size_t)c * 32];
      }
      asm volatile("" :: "v"(dummy));
    }
    attn_tile(wv, obase);
    if (it == 0) writech(xst + (g * 2) * XLSZ);  // stage next chunk0 into buf0
    attn_tile(15 - wv, obase);
  }
}

extern "C" void kernel_launch(void* const* d_in, const int* in_sizes, int n_in,
                              void* d_out, int out_size, void* d_ws, size_t ws_size,
                              hipStream_t stream) {
  const float* x  = (const float*)d_in[0];
  const float* Wq = (const float*)d_in[1];
  const float* Wk = (const float*)d_in[2];
  const float* Wv = (const float*)d_in[3];
  float* out = (float*)d_out;

  short* wfrag = (short*)d_ws;

  prep_w_kernel<<<36, 256, 0, stream>>>(Wq, Wk, Wv, wfrag);
  fused_kernel<<<256, 512, 0, stream>>>(x, wfrag, out);
}

// Round 12
// 56.363 us; speedup vs baseline: 2.2308x; 2.2308x over previous
//
#include <hip/hip_runtime.h>
#include <hip/hip_bf16.h>

// Problem: B=512, S=256, E=384, H=64.
// d_in: x [B,S,E] f32; Wq,Wk,Wv [E,H] f32.  d_out: [B,S,H] f32.
// ws: [0, 147456) wfrag bf16 (only region used).
//
// FUSED v12: 12 waves/CU with an allocator-proof af.
// The session's one validated lever is waves/CU (4w:115 -> 8w:57); every
// >8-wave attempt died to af demotion (v6/v8/v11: VGPR 84-128 < af size).
// Fix: 12-way n-split -> af[12][1] = 48 VGPR/wave (each wave owns ONE
// h-tile f=wv; all 12 waves cooperate per 16-row chunk). Proj live set
// ~85 VGPR -- below even the allocator's aggressive 128 target.
// LDS 96 KB QKV + 24.5 KB staging dbuf = 121 KB -> 1 block/CU, 3 w/SIMD.
// Verified parts reused verbatim: v10 lgkm-only barrier + dbuf invariant,
// v10 attention tile, v6 12-wave causal partition, af pin.

#define NB   512
#define SS   256
#define EE   384
#define HH   64

#define PR16  16            // x rows staged per chunk
#define LROW  392           // staging row stride in shorts (384 data + 8 pad)
#define XLSZ  (PR16 * LROW) // 6272 shorts per staging buffer

// lgkm-only barrier: LDS writes retired, global loads ride through (v10-verified).
#define SYNC_LDS() asm volatile("s_waitcnt lgkmcnt(0)\n\ts_barrier" ::: "memory")

typedef short bf16x8 __attribute__((ext_vector_type(8)));
typedef float f32x4  __attribute__((ext_vector_type(4)));

__device__ __forceinline__ short f2bf(float f) {
  union { float f; unsigned u; } x; x.f = f;
  unsigned r = x.u + 0x7fffu + ((x.u >> 16) & 1u);
  return (short)(r >> 16);
}

// ---------------- prep: W -> fragment-ordered bf16 (unchanged) ----------------
// wfrag[((ks*12+nf)*64 + lane)*8 + j] = Wcat[ks*32 + (lane>>4)*8 + j][nf*16 + (lane&15)]
__global__ __launch_bounds__(256) void prep_w_kernel(
    const float* __restrict__ Wq, const float* __restrict__ Wk,
    const float* __restrict__ Wv, short* __restrict__ wfrag) {
  int t = blockIdx.x * 256 + threadIdx.x;
  if (t >= 12 * 12 * 64) return;
  int ks  = t / (12 * 64);
  int rem = t % (12 * 64);
  int nf  = rem / 64;
  int l   = rem % 64;
  int l15 = l & 15, lhi = l >> 4;
  int ncat = nf * 16 + l15;
  const float* W = (ncat < 64) ? Wq : (ncat < 128 ? Wk : Wv);
  int n = ncat & 63;
  short* dst = wfrag + (size_t)t * 8;
#pragma unroll
  for (int j = 0; j < 8; ++j) {
    int kk = ks * 32 + lhi * 8 + j;
    dst[j] = f2bf(W[kk * 64 + n]);
  }
}

// ---------------- fused: one block = one batch, 12 waves, 121 KB LDS ----------------
__global__ __launch_bounds__(768, 3) void fused_kernel(
    const float* __restrict__ x, const short* __restrict__ wfrag,
    float* __restrict__ out) {
  // Ql swizzled: elem (row,h) at Ql[row*64 + (h ^ ((row&7)<<3))]       (v2..v10-verified)
  // Kl swizzled: elem (row,h) at Kl[row*64 + (h ^ (srow<<3))], srow=((row&8)>>1)|(row&3)
  // Vt swizzled: elem (h,row) at Vt[h*256 + (row ^ ((h&7)<<3))]
  // xst: dbuf of 16-row x tiles, padded stride LROW=392 (whole block cooperates)
  __shared__ __align__(16) short Ql[SS * HH];    // 32 KB
  __shared__ __align__(16) short Kl[SS * HH];    // 32 KB
  __shared__ __align__(16) short Vt[HH * SS];    // 32 KB
  __shared__ __align__(16) short xst[2 * XLSZ];  // 24.5 KB -> 123904 B total

  int b    = blockIdx.x;
  int tid  = threadIdx.x;
  int lane = tid & 63, wv = tid >> 6;            // wv in [0,12)
  int l15  = lane & 15, lhi = lane >> 4;
  int sw   = l15 & 7;
  const float* xb = x + (size_t)b * SS * EE;

  // ---- W fragments: ONE h-tile per wave (f = wv) -> af[12] = 48 VGPR, pinned ----
  bf16x8 af[12];
#pragma unroll
  for (int ks = 0; ks < 12; ++ks)
    af[ks] = *(const bf16x8*)(wfrag + ((size_t)(ks * 12 + wv) * 64 + lane) * 8);
#pragma unroll
  for (int ks = 0; ks < 12; ++ks)
    asm volatile("" : "+v"(af[ks]));

  f32x4 st[2];
  auto loadch = [&](int ch) {  // 16 rows = 24 KB f32, 32 B/thread, fully contiguous
    const float* p0 = xb + (size_t)ch * PR16 * EE;
    const f32x4* p = (const f32x4*)(p0 + (size_t)tid * 8);
    st[0] = p[0];
    st[1] = p[1];
  };
  auto writech = [&](short* xl) {  // regs -> bf16 -> padded LDS tile, 1 store/thread
    int row = tid / 48, cg = tid % 48;   // 768 = 16 rows x 48 8-float groups
    union { bf16x8 vv; __hip_bfloat162 h2[4]; } u;
    u.h2[0] = __float22bfloat162_rn(make_float2(st[0][0], st[0][1]));
    u.h2[1] = __float22bfloat162_rn(make_float2(st[0][2], st[0][3]));
    u.h2[2] = __float22bfloat162_rn(make_float2(st[1][0], st[1][1]));
    u.h2[3] = __float22bfloat162_rn(make_float2(st[1][2], st[1][3]));
    *(bf16x8*)(xl + row * LROW + cg * 8) = u.vv;
  };

  // ---- projection: 16 chunks of 16 rows, dbuf, ONE lgkm-barrier per chunk ----
  // Single-barrier safety (v7/v10-verified): writech(ch+1) targets the opposite
  // buffer of the one being read; reads of that buffer happened in iteration
  // ch-1 and are retired by the barrier at iteration ch's top.
  loadch(0);
  writech(xst);
  for (int ch = 0; ch < 16; ++ch) {
    if (ch < 15) loadch(ch + 1);     // next chunk's loads ride through the barrier
    SYNC_LDS();                      // LDS visible; vmcnt untouched
    const short* xl = xst + (ch & 1) * XLSZ;

    f32x4 acc = (f32x4){0.f, 0.f, 0.f, 0.f};
#pragma unroll
    for (int ks = 0; ks < 12; ++ks) {
      bf16x8 bx = *(const bf16x8*)(xl + l15 * LROW + ks * 32 + lhi * 8);
      acc = __builtin_amdgcn_mfma_f32_16x16x32_bf16(af[ks], bx, acc, 0, 0, 0);
    }

    // epilogue: f = wv (wave-uniform), ncat = wv*16 + lhi*4, row = ch*16+l15
    int row  = ch * PR16 + l15;
    int srow = ((row & 8) >> 1) | (row & 3);
    int ncat = wv * 16 + lhi * 4;
    if (wv < 4) {          // Q -> Ql, row&7 swizzle
      union { short4 s4; __hip_bfloat162 h2[2]; } oq;
      oq.h2[0] = __float22bfloat162_rn(make_float2(acc[0], acc[1]));
      oq.h2[1] = __float22bfloat162_rn(make_float2(acc[2], acc[3]));
      *(short4*)(Ql + row * 64 + (ncat ^ ((row & 7) << 3))) = oq.s4;
    } else if (wv < 8) {   // K -> Kl, srow swizzle
      int col = ncat - 64;
      union { short4 s4; __hip_bfloat162 h2[2]; } ok;
      ok.h2[0] = __float22bfloat162_rn(make_float2(acc[0], acc[1]));
      ok.h2[1] = __float22bfloat162_rn(make_float2(acc[2], acc[3]));
      *(short4*)(Kl + row * 64 + (col ^ (srow << 3))) = ok.s4;
    } else {               // V -> Vt transposed, scalar stores
#pragma unroll
      for (int j = 0; j < 4; ++j) {
        int h = ncat - 128 + j;
        Vt[h * 256 + (row ^ ((h & 7) << 3))] = f2bf(acc[j]);
      }
    }
    if (ch < 15) writech(xst + ((ch + 1) & 1) * XLSZ);
  }
  SYNC_LDS();                        // Ql/Kl/Vt complete (17th and last barrier)

  // ---- attention: 12-wave balanced causal partition (v6-verified), in-lane P ----
  // w0:{15} w1:{14} w2:{13} w3:{12} w4:{11,0} w5:{10,1} w6:{9,2} w7:{8,3}
  // w8:{7,4} w9:{6,5} w10,w11: idle
  int nt, rt0 = 0, rt1 = 0;
  if (wv < 4)       { nt = 1; rt0 = 15 - wv; }
  else if (wv < 10) { nt = 2; rt0 = 15 - wv; rt1 = wv - 4; }
  else              { nt = 0; }

  size_t obase = (size_t)b * SS * HH;
  for (int u = 0; u < nt; ++u) {
    int rt    = (u == 0) ? rt0 : rt1;
    int qrow0 = rt * 16;
    int twp   = (rt + 2) & ~1;       // even # of interleaved 16-row k-tiles
    int nk    = twp >> 1;            // 32-k PV chunks
    int qg    = qrow0 + l15;         // this lane's q-row (P lives at q=l15)

    // Q fragments from swizzled Ql
    int qlrow = qrow0 + l15;
    bf16x8 qa0 = *(const bf16x8*)(Ql + qlrow * 64 + ((lhi * 8) ^ ((qlrow & 7) << 3)));
    bf16x8 qa1 = *(const bf16x8*)(Ql + qlrow * 64 + ((32 + lhi * 8) ^ ((qlrow & 7) << 3)));

    // scores: tile t loads K rows kc = (t>>1)*32 + (l15>>2)*8 + (t&1)*4 + (l15&3)
    // (interleaved mapping: srow(kc) == sw, and D-layout == PV A-fragment)
    f32x4 s[16];
#pragma unroll
    for (int t = 0; t < 16; ++t) {
      if (t >= twp) continue;
      int kc = (t >> 1) * 32 + ((l15 >> 2) << 3) + ((t & 1) << 2) + (l15 & 3);
      const short* kp = Kl + kc * 64;
      bf16x8 kb0 = *(const bf16x8*)(kp + ((lhi * 8) ^ (sw << 3)));
      bf16x8 kb1 = *(const bf16x8*)(kp + ((32 + lhi * 8) ^ (sw << 3)));
      __builtin_amdgcn_s_setprio(1);
      f32x4 a = (f32x4){0.f, 0.f, 0.f, 0.f};
      a = __builtin_amdgcn_mfma_f32_16x16x32_bf16(kb0, qa0, a, 0, 0, 0);
      a = __builtin_amdgcn_mfma_f32_16x16x32_bf16(kb1, qa1, a, 0, 0, 0);
      __builtin_amdgcn_s_setprio(0);
#pragma unroll
      for (int r = 0; r < 4; ++r) {
        int kg = (t >> 1) * 32 + lhi * 8 + ((t & 1) << 2) + r;
        s[t][r] = (kg <= qg) ? a[r] * 0.125f : -INFINITY;
      }
    }

    // softmax over lane-local row (q=l15), reduce across lhi groups
    float mx = -3.0e38f;
#pragma unroll
    for (int t = 0; t < 16; ++t) {
      if (t >= twp) continue;
#pragma unroll
      for (int r = 0; r < 4; ++r) mx = fmaxf(mx, s[t][r]);
    }
    mx = fmaxf(mx, __shfl_xor(mx, 16));
    mx = fmaxf(mx, __shfl_xor(mx, 32));
    float sm = 0.f;
#pragma unroll
    for (int t = 0; t < 16; ++t) {
      if (t >= twp) continue;
#pragma unroll
      for (int r = 0; r < 4; ++r) {
        float p = __expf(s[t][r] - mx);    // exp(-inf)=0
        s[t][r] = p;
        sm += p;
      }
    }
    sm += __shfl_xor(sm, 16);
    sm += __shfl_xor(sm, 32);
    float inv = 1.f / sm;
    float invq[4];
#pragma unroll
    for (int r = 0; r < 4; ++r) invq[r] = __shfl(inv, lhi * 4 + r);

    // PV: pack P in-lane (no LDS), accumulate
    f32x4 o[4];
#pragma unroll
    for (int nf = 0; nf < 4; ++nf) o[nf] = (f32x4){0.f, 0.f, 0.f, 0.f};
#pragma unroll
    for (int kc2 = 0; kc2 < 8; ++kc2) {
      if (kc2 >= nk) continue;
      union { bf16x8 v; __hip_bfloat162 h2[4]; } pu;
      pu.h2[0] = __float22bfloat162_rn(make_float2(s[2*kc2][0],   s[2*kc2][1]));
      pu.h2[1] = __float22bfloat162_rn(make_float2(s[2*kc2][2],   s[2*kc2][3]));
      pu.h2[2] = __float22bfloat162_rn(make_float2(s[2*kc2+1][0], s[2*kc2+1][1]));
      pu.h2[3] = __float22bfloat162_rn(make_float2(s[2*kc2+1][2], s[2*kc2+1][3]));
      int kofs = kc2 * 32 + lhi * 8;
      __builtin_amdgcn_s_setprio(1);
#pragma unroll
      for (int nf = 0; nf < 4; ++nf) {
        int hrow = nf * 16 + l15;
        bf16x8 vb = *(const bf16x8*)(Vt + hrow * 256 + (kofs ^ ((hrow & 7) << 3)));
        o[nf] = __builtin_amdgcn_mfma_f32_16x16x32_bf16(pu.v, vb, o[nf], 0, 0, 0);
      }
      __builtin_amdgcn_s_setprio(0);
    }

    // store (divide by row sum here)
#pragma unroll
    for (int nf = 0; nf < 4; ++nf)
#pragma unroll
      for (int r = 0; r < 4; ++r) {
        int q = qrow0 + lhi * 4 + r;
        int h = nf * 16 + l15;
        out[obase + (size_t)q * HH + h] = o[nf][r] * invq[r];
      }
  }
}

extern "C" void kernel_launch(void* const* d_in, const int* in_sizes, int n_in,
                              void* d_out, int out_size, void* d_ws, size_t ws_size,
                              hipStream_t stream) {
  const float* x  = (const float*)d_in[0];
  const float* Wq = (const float*)d_in[1];
  const float* Wk = (const float*)d_in[2];
  const float* Wv = (const float*)d_in[3];
  float* out = (float*)d_out;

  short* wfrag = (short*)d_ws;

  prep_w_kernel<<<36, 256, 0, stream>>>(Wq, Wk, Wv, wfrag);
  fused_kernel<<<512, 768, 0, stream>>>(x, wfrag, out);
}